// Round 5
// baseline (677.172 us; speedup 1.0000x reference)
//
#include <hip/hip_runtime.h>

#define NROW 8192
#define F 256
#define BM 16
#define BK 128
#define NSTEP (NROW / BK)   // 64

typedef __attribute__((ext_vector_type(8))) short bf16x8;
typedef __attribute__((ext_vector_type(4))) float f32x4;
typedef __attribute__((ext_vector_type(4))) int i32x4;

__device__ __forceinline__ unsigned short f2bf(float f) {
  union { float f; unsigned int u; } v; v.f = f;
  unsigned int u = v.u;
  u += 0x7fffu + ((u >> 16) & 1u);   // RNE
  return (unsigned short)(u >> 16);
}

// fp32 [R][C] -> bf16 [C][R]
__global__ __launch_bounds__(256) void transpose_cvt(const float* __restrict__ in,
                                                     unsigned short* __restrict__ outT,
                                                     int R, int C) {
  __shared__ float tile[32][33];
  const int r0 = blockIdx.x << 5, c0 = blockIdx.y << 5;
  const int t = threadIdx.x;
  const int rr = t >> 3, cc = (t & 7) << 2;
  float4 v = *(const float4*)(in + (size_t)(r0 + rr) * C + c0 + cc);
  tile[rr][cc + 0] = v.x; tile[rr][cc + 1] = v.y;
  tile[rr][cc + 2] = v.z; tile[rr][cc + 3] = v.w;
  __syncthreads();
  ushort4 o;
  o.x = f2bf(tile[cc + 0][rr]);
  o.y = f2bf(tile[cc + 1][rr]);
  o.z = f2bf(tile[cc + 2][rr]);
  o.w = f2bf(tile[cc + 3][rr]);
  *(ushort4*)(outT + (size_t)(c0 + rr) * R + r0 + cc) = o;
}

__global__ __launch_bounds__(512, 4) void gat_main(
    const float* __restrict__ att, const int* __restrict__ adj,
    const unsigned short* __restrict__ Bt, const unsigned short* __restrict__ Wt,
    const float* __restrict__ bias, float* __restrict__ out) {

  __shared__ alignas(16) unsigned short ldsA[2][BM * BK];  // 2 x 4 KB
  __shared__ alignas(16) unsigned short ldsX[BM * F];      // 8 KB

  const int tid = threadIdx.x;
  const int lane = tid & 63;
  const int w = tid >> 6;            // wave 0..7 -> 32-col slab
  const int colbase = w << 5;
  const int row0 = blockIdx.x * BM;

  // staging coords: thread handles row ar, float4 chunk ac (of 32)
  const int ar = tid >> 5;           // 0..15
  const int ac = tid & 31;           // 0..31
  const int awbyte = ar * 256 + ((((ac >> 1) ^ (ar & 7))) << 4) + ((ac & 1) << 3);
  const float* ap = att + (size_t)(row0 + ar) * NROW + (ac << 2);
  const int*   jp = adj + (size_t)(row0 + ar) * NROW + (ac << 2);

  // fragment coords
  const int r = lane & 15;
  const int hi = lane >> 4;          // 0..3

  f32x4 acc[2];
  acc[0] = (f32x4){0.f, 0.f, 0.f, 0.f};
  acc[1] = (f32x4){0.f, 0.f, 0.f, 0.f};

  auto loadA = [&](int t, f32x4& fv, i32x4& jv) {
    fv = __builtin_nontemporal_load((const f32x4*)(ap + (size_t)t * BK));
    jv = __builtin_nontemporal_load((const i32x4*)(jp + (size_t)t * BK));
  };
  auto stage = [&](unsigned short* bufA, const f32x4& fv, const i32x4& jv) {
    ushort4 pk;
    pk.x = f2bf(jv.x ? fv.x : 0.f);
    pk.y = f2bf(jv.y ? fv.y : 0.f);
    pk.z = f2bf(jv.z ? fv.z : 0.f);
    pk.w = f2bf(jv.w ? fv.w : 0.f);
    *(ushort4*)((char*)bufA + awbyte) = pk;
  };
  auto compute = [&](const unsigned short* bufA, int kb) {
#pragma unroll
    for (int ks = 0; ks < 4; ++ks) {
      const int kk = (ks << 2) + hi;
      bf16x8 afrag = *(const bf16x8*)((const char*)bufA + r * 256 + ((kk ^ (r & 7)) << 4));
      const int kg = kb + (ks << 5) + (hi << 3);
#pragma unroll
      for (int nt = 0; nt < 2; ++nt) {
        const int n = colbase + (nt << 4) + r;
        bf16x8 bfrag = *(const bf16x8*)(Bt + ((size_t)n << 13) + kg);
        acc[nt] = __builtin_amdgcn_mfma_f32_16x16x32_bf16(afrag, bfrag, acc[nt], 0, 0, 0);
      }
    }
  };

  // ---- register double-pipeline over 64 K-tiles
  f32x4 fa, fb; i32x4 ja, jb;
  loadA(0, fa, ja);
  loadA(1, fb, jb);
  stage(ldsA[0], fa, ja);
  __syncthreads();

#pragma unroll 1
  for (int t = 0; t < NSTEP - 2; t += 2) {
    loadA(t + 2, fa, ja);
    compute(ldsA[0], t * BK);
    stage(ldsA[1], fb, jb);
    __syncthreads();
    loadA(t + 3, fb, jb);
    compute(ldsA[1], (t + 1) * BK);
    stage(ldsA[0], fa, ja);
    __syncthreads();
  }
  compute(ldsA[0], (NSTEP - 2) * BK);
  stage(ldsA[1], fb, jb);
  __syncthreads();
  compute(ldsA[1], (NSTEP - 1) * BK);

  // ---- fused GEMM2: out = relu(x @ W + b)
#pragma unroll
  for (int nt = 0; nt < 2; ++nt) {
#pragma unroll
    for (int b = 0; b < 4; ++b) {
      const int xr = (hi << 2) + b;
      const int c = colbase + (nt << 4) + r;
      const int kk2 = c >> 3;
      const int byte = xr * 512 + ((kk2 ^ (xr & 7)) << 4) + ((c & 7) << 1);
      *(unsigned short*)((char*)ldsX + byte) = f2bf(acc[nt][b]);
    }
  }
  __syncthreads();

  f32x4 acc2[2];
#pragma unroll
  for (int nt = 0; nt < 2; ++nt) {
    const float bv = bias[colbase + (nt << 4) + r];
    acc2[nt] = (f32x4){bv, bv, bv, bv};
  }
#pragma unroll
  for (int ks2 = 0; ks2 < 8; ++ks2) {
    const int kk2 = (ks2 << 2) + hi;
    bf16x8 a2 = *(const bf16x8*)((char*)ldsX + r * 512 + ((kk2 ^ (r & 7)) << 4));
    const int kg = (ks2 << 5) + (hi << 3);
#pragma unroll
    for (int nt = 0; nt < 2; ++nt) {
      const int n = colbase + (nt << 4) + r;
      bf16x8 w2 = *(const bf16x8*)(Wt + ((size_t)n << 8) + kg);
      acc2[nt] = __builtin_amdgcn_mfma_f32_16x16x32_bf16(a2, w2, acc2[nt], 0, 0, 0);
    }
  }
#pragma unroll
  for (int nt = 0; nt < 2; ++nt) {
#pragma unroll
    for (int b = 0; b < 4; ++b) {
      const int rr = row0 + (hi << 2) + b;
      const int c = colbase + (nt << 4) + r;
      out[(size_t)rr * F + c] = fmaxf(acc2[nt][b], 0.f);
    }
  }
}

extern "C" void kernel_launch(void* const* d_in, const int* in_sizes, int n_in,
                              void* d_out, int out_size, void* d_ws, size_t ws_size,
                              hipStream_t stream) {
  const int* adj = (const int*)d_in[0];
  const float* x_in = (const float*)d_in[1];
  const float* att = (const float*)d_in[2];
  const float* W = (const float*)d_in[3];
  const float* b = (const float*)d_in[4];
  float* out = (float*)d_out;

  unsigned short* Bt = (unsigned short*)d_ws;                                    // 256x8192 bf16, 4 MB
  unsigned short* Wt = (unsigned short*)((char*)d_ws + (size_t)256 * 8192 * 2);  // 256x256 bf16

  dim3 g1(NROW / 32, F / 32);
  transpose_cvt<<<g1, 256, 0, stream>>>(x_in, Bt, NROW, F);
  dim3 g2(F / 32, F / 32);
  transpose_cvt<<<g2, 256, 0, stream>>>(W, Wt, F, F);
  gat_main<<<NROW / BM, 512, 0, stream>>>(att, adj, Bt, Wt, b, out);
}